// Round 18
// baseline (861.410 us; speedup 1.0000x reference)
//
#include <hip/hip_runtime.h>
#include <hip/hip_bf16.h>
#include <math.h>

// Problem constants
#define BB     256
#define NMEL   80
#define TMEL   800
#define NFR    16          // frames per step
#define TT     50          // decoder steps
#define RNN    1024
#define ENC    256
#define INDIM  1280        // RNN + ENC == MEL_DIM
#define G4     4096        // 4*RNN
#define MROWS  (TT*BB)     // 12800

typedef __attribute__((ext_vector_type(8))) short bf16x8;
typedef __attribute__((ext_vector_type(4))) float f32x4;

#define GAS __attribute__((address_space(1)))
#define LAS __attribute__((address_space(3)))

__device__ __forceinline__ unsigned short f2bf(float f) {
    unsigned int u = __float_as_uint(f);
    u += 0x7FFFu + ((u >> 16) & 1u);     // round-to-nearest-even
    return (unsigned short)(u >> 16);
}
__device__ __forceinline__ float bf2f(unsigned short s) {
    return __uint_as_float(((unsigned int)s) << 16);
}
__device__ __forceinline__ float fsig(float x) {      // inf-safe fast sigmoid
    return 1.f / (1.f + __expf(-x));
}
__device__ __forceinline__ float ftanh(float x) {     // tanh = 2*sig(2x)-1
    return 2.f / (1.f + __expf(-2.f * x)) - 1.f;
}

// ---------------- prep kernels ----------------

// vectorized f32 -> bf16 (n4 = n/4 16B-chunks)
__global__ void k_f32_to_bf16(const float* __restrict__ src,
                              unsigned short* __restrict__ dst, int n4) {
    for (int i = blockIdx.x * blockDim.x + threadIdx.x; i < n4;
         i += gridDim.x * blockDim.x) {
        f32x4 v = *(const f32x4*)(src + (size_t)i * 4);
        unsigned long long p = (unsigned long long)f2bf(v[0]) |
                               ((unsigned long long)f2bf(v[1]) << 16) |
                               ((unsigned long long)f2bf(v[2]) << 32) |
                               ((unsigned long long)f2bf(v[3]) << 48);
        *(unsigned long long*)(dst + (size_t)i * 4) = p;
    }
}

// W_proj[:, 0:1024] -> bf16, N-permuted: dst row m' = mel*16+fr comes from
// W_proj row m = fr*80+mel. 4-wide chunks.
__global__ void k_conv_wph(const float* __restrict__ wproj,
                           unsigned short* __restrict__ dst) {
    const int n4 = INDIM * RNN / 4;
    for (int i = blockIdx.x * blockDim.x + threadIdx.x; i < n4;
         i += gridDim.x * blockDim.x) {
        int mp = i >> 8, kc = (i & 255) * 4;
        int mel = mp >> 4, fr = mp & 15;
        f32x4 v = *(const f32x4*)(wproj + (size_t)(fr * NMEL + mel) * INDIM + kc);
        unsigned long long p = (unsigned long long)f2bf(v[0]) |
                               ((unsigned long long)f2bf(v[1]) << 16) |
                               ((unsigned long long)f2bf(v[2]) << 32) |
                               ((unsigned long long)f2bf(v[3]) << 48);
        *(unsigned long long*)(dst + (size_t)i * 4) = p;
    }
}

// W_proj[:, 1024:1280] -> bf16 [1280][256], rows permuted m' = mel*16+fr.
__global__ void k_conv_wpc(const float* __restrict__ wproj,
                           unsigned short* __restrict__ dst) {
    const int n4 = INDIM * ENC / 4;                 // 81920 chunks
    for (int i = blockIdx.x * blockDim.x + threadIdx.x; i < n4;
         i += gridDim.x * blockDim.x) {
        int mp = i >> 6, kc = (i & 63) * 4;
        int mel = mp >> 4, fr = mp & 15;
        f32x4 v = *(const f32x4*)(wproj + (size_t)(fr * NMEL + mel) * INDIM +
                                  RNN + kc);
        unsigned long long p = (unsigned long long)f2bf(v[0]) |
                               ((unsigned long long)f2bf(v[1]) << 16) |
                               ((unsigned long long)f2bf(v[2]) << 32) |
                               ((unsigned long long)f2bf(v[3]) << 48);
        *(unsigned long long*)(dst + (size_t)i * 4) = p;
    }
}

// teacher-forced inputs via LDS transpose tile: WG per (t,b).
// frames[t][b][k] = (t==0)?0:target[b][k%80][t*16+k/80]
__global__ __launch_bounds__(128) void k_frames(const float* __restrict__ target,
                                                unsigned short* __restrict__ frames) {
    const int wg = blockIdx.x;              // 0..12799
    const int t = wg >> 8, b = wg & 255;
    unsigned short* dst = frames + ((size_t)t * BB + b) * INDIM;
    if (t == 0) {
        for (int i = threadIdx.x; i < INDIM / 8; i += 128)
            *(f32x4*)(dst + i * 8) = (f32x4){0.f, 0.f, 0.f, 0.f};
        return;
    }
    __shared__ float ld[NMEL][17];
    for (int i = threadIdx.x; i < 320; i += 128) {    // 80 mel x 4 f32x4
        const int mel = i >> 2, fq = i & 3;
        f32x4 v = *(const f32x4*)(target + ((size_t)b * NMEL + mel) * TMEL +
                                  t * NFR + fq * 4);
        #pragma unroll
        for (int j = 0; j < 4; ++j) ld[mel][fq * 4 + j] = v[j];
    }
    __syncthreads();
    for (int i = threadIdx.x; i < 160; i += 128) {    // 160 x 8-short chunks
        unsigned long long p0 = 0, p1 = 0;
        #pragma unroll
        for (int j = 0; j < 4; ++j) {
            const int k = i * 8 + j;
            p0 |= (unsigned long long)f2bf(ld[k % 80][k / 80]) << (16 * j);
        }
        #pragma unroll
        for (int j = 0; j < 4; ++j) {
            const int k = i * 8 + 4 + j;
            p1 |= (unsigned long long)f2bf(ld[k % 80][k / 80]) << (16 * j);
        }
        *(unsigned long long*)(dst + i * 8) = p0;
        *(unsigned long long*)(dst + i * 8 + 4) = p1;
    }
}

// gatectx[b] = b_gate + context[b]·W_gate[0][1024:1280]
__global__ void k_gatectx(const float* __restrict__ context,
                          const float* __restrict__ wgate,
                          const float* __restrict__ bgate,
                          float* __restrict__ gctx) {
    int b = blockIdx.x * blockDim.x + threadIdx.x;
    if (b >= BB) return;
    float acc = bgate[0];
    const float* cb = context + b * ENC;
    for (int e = 0; e < ENC; ++e) acc += cb[e] * wgate[RNN + e];
    gctx[b] = acc;
}

// ---------------- GEMM core v4: m97 geometry + blocked LDS layout ----------
// 128x128 WG tile, BK=32, 256 thr / 4 waves (wave -> 64x64, acc[4][4] ->
// 0.5 ds_read per MFMA, vs core2's 0.75). 3 x 16KB buffers (48KB -> 3 WG/CU)
// with the v9 merged-single-barrier schedule:
//   vmcnt(4) -> lgkmcnt(0) -> s_barrier -> STAGE(it+2) -> compute(it)
// LDS layout is BLOCK-TRANSPOSED: chunk (row, ksub q) of a 128x32 tile lives
// at slot (row>>4)*64 + q*16 + (row&15). Every fragment read is then
// base + lane*16B — perfectly linear, conflict-free by construction (at
// BK=32 the 64B row stride aliases banks every 2 rows, so XOR can't fix it;
// the layout permutation can). Staging source encodes the permutation
// per-lane; LDS dest stays linear (both-sides rule #21).
template<int STRIDE, int KDIM>
__device__ __forceinline__ void gemm_core4(const unsigned short* __restrict__ A,
                                           const unsigned short* __restrict__ Bw,
                                           int mblk, int nblk,
                                           unsigned short* As,   // [3][4096]
                                           unsigned short* Bs,   // [3][4096]
                                           f32x4 acc[4][4]) {
    const int tid = threadIdx.x, lane = tid & 63, w = tid >> 6;
    const int wm = (w >> 1) * 64, wn = (w & 1) * 64;
    // staging: operand tile = 512 chunks of 16B. Thread stages chunks
    // c1 = tid, c2 = tid+256. Chunk c -> global row = (c>>6)*16 + (c&15),
    // k-offset = ((c>>4)&3)*8 shorts. LDS dst linear at c*16B.
    const int c1 = tid, c2 = tid + 256;
    const int r1 = (c1 >> 6) * 16 + (c1 & 15), k1 = ((c1 >> 4) & 3) * 8;
    const int r2 = (c2 >> 6) * 16 + (c2 & 15), k2 = ((c2 >> 4) & 3) * 8;
    const unsigned short* a1p = A + (size_t)(mblk + r1) * STRIDE + k1;
    const unsigned short* a2p = A + (size_t)(mblk + r2) * STRIDE + k2;
    const unsigned short* b1p = Bw + (size_t)(nblk + r1) * STRIDE + k1;
    const unsigned short* b2p = Bw + (size_t)(nblk + r2) * STRIDE + k2;

#define GSTAGE(buf, k0) do {                                                   \
    __builtin_amdgcn_global_load_lds((const GAS unsigned int*)(a1p + (k0)),    \
        (LAS unsigned int*)(As + (buf) * 4096 + w * 512), 16, 0, 0);           \
    __builtin_amdgcn_global_load_lds((const GAS unsigned int*)(a2p + (k0)),    \
        (LAS unsigned int*)(As + (buf) * 4096 + 2048 + w * 512), 16, 0, 0);    \
    __builtin_amdgcn_global_load_lds((const GAS unsigned int*)(b1p + (k0)),    \
        (LAS unsigned int*)(Bs + (buf) * 4096 + w * 512), 16, 0, 0);           \
    __builtin_amdgcn_global_load_lds((const GAS unsigned int*)(b2p + (k0)),    \
        (LAS unsigned int*)(Bs + (buf) * 4096 + 2048 + w * 512), 16, 0, 0); } while (0)

    constexpr int NIT = KDIM / 32;
    GSTAGE(0, 0); GSTAGE(1, 32);
    #pragma unroll 4
    for (int it = 0; it < NIT; ++it) {
        // wait for stage(it); stage(it+1) (4 ops) may stay in flight
        if (it < NIT - 1) asm volatile("s_waitcnt vmcnt(4)" ::: "memory");
        else              asm volatile("s_waitcnt vmcnt(0)" ::: "memory");
        asm volatile("s_waitcnt lgkmcnt(0)" ::: "memory");  // it-1 reads done
        asm volatile("s_barrier" ::: "memory");
        __builtin_amdgcn_sched_barrier(0);
        if (it <= NIT - 3) GSTAGE((it + 2) % 3, (it + 2) * 32);
        const unsigned short* Ab = As + (it % 3) * 4096;
        const unsigned short* Bb = Bs + (it % 3) * 4096;
        bf16x8 af[4], bv[4];
        #pragma unroll
        for (int mi = 0; mi < 4; ++mi)      // linear: base + lane*16B
            af[mi] = *(const bf16x8*)(Ab + ((wm >> 4) + mi) * 512 + lane * 8);
        #pragma unroll
        for (int ni = 0; ni < 4; ++ni)
            bv[ni] = *(const bf16x8*)(Bb + ((wn >> 4) + ni) * 512 + lane * 8);
        #pragma unroll
        for (int mi = 0; mi < 4; ++mi)
            #pragma unroll
            for (int ni = 0; ni < 4; ++ni)
                acc[mi][ni] = __builtin_amdgcn_mfma_f32_16x16x32_bf16(
                    af[mi], bv[ni], acc[mi][ni], 0, 0, 0);
    }
#undef GSTAGE
}

// GEMM 1: xproj = frames @ W_ih^T + b_ih + b_hh (bf16 out). M=12800 N=4096 K=1280
__global__ __launch_bounds__(256) void k_gemm_xproj(
    const unsigned short* __restrict__ A,   // [12800][1280]
    const unsigned short* __restrict__ Bw,  // [4096][1280]
    const float* __restrict__ b_ih, const float* __restrict__ b_hh,
    unsigned short* __restrict__ Cout)      // [12800][4096]
{
    __shared__ unsigned short As[3][4096], Bs[3][4096];   // 48KB
    f32x4 acc[4][4] = {};
    const int mblk = blockIdx.y * 128, nblk = blockIdx.x * 128;
    gemm_core4<INDIM, INDIM>(A, Bw, mblk, nblk, &As[0][0], &Bs[0][0], acc);
    const int lane = threadIdx.x & 63, w = threadIdx.x >> 6;
    const int wm = (w >> 1) * 64, wn = (w & 1) * 64;
    const int lr = lane & 15, q = lane >> 4;
    #pragma unroll
    for (int ni = 0; ni < 4; ++ni) {
        const int col = nblk + wn + ni * 16 + lr;
        const float bias = b_ih[col] + b_hh[col];
        #pragma unroll
        for (int mi = 0; mi < 4; ++mi) {
            const int row0 = mblk + wm + mi * 16 + q * 4;
            #pragma unroll
            for (int r = 0; r < 4; ++r)
                Cout[(size_t)(row0 + r) * G4 + col] = f2bf(acc[mi][ni][r] + bias);
        }
    }
}

// GEMM 2: mel = h_all[1:] @ Wp'^T + ctxproj'. txp is wave-private -> no
// __syncthreads in the epilogue (same-wave LDS deps ordered by lgkmcnt).
__global__ __launch_bounds__(256) void k_gemm_mel(
    const unsigned short* __restrict__ A,   // [12800][1024]
    const unsigned short* __restrict__ Bw,  // Wp' [1280][1024] (permuted)
    const float* __restrict__ ctxproj,      // [256][1280] (permuted)
    float* __restrict__ out0)               // [256][80][800]
{
    __shared__ unsigned short As[3][4096], Bs[3][4096];   // 48KB
    __shared__ float txp[4][16][20];        // per-wave transpose (5.1KB)
    f32x4 acc[4][4] = {};
    const int mblk = blockIdx.y * 128, nblk = blockIdx.x * 128;
    gemm_core4<RNN, RNN>(A, Bw, mblk, nblk, &As[0][0], &Bs[0][0], acc);
    const int lane = threadIdx.x & 63, w = threadIdx.x >> 6;
    const int wm = (w >> 1) * 64, wn = (w & 1) * 64;
    const int lr = lane & 15, q = lane >> 4;
    const int rbase = q * 4;
    const int rowl = lane & 15, fq = lane >> 4;   // readback roles
    #pragma unroll
    for (int mi = 0; mi < 4; ++mi) {
        const int row0 = mblk + wm + mi * 16;     // 16 rows: same t, b0..b0+15
        const int t = row0 >> 8, b0 = row0 & 255;
        #pragma unroll
        for (int ni = 0; ni < 4; ++ni) {
            const int colbase = nblk + wn + ni * 16;  // one mel, fr 0..15
            const int mel = colbase >> 4;
            #pragma unroll
            for (int r = 0; r < 4; ++r)
                txp[w][rbase + r][lr] = acc[mi][ni][r];
            const int bL = b0 + rowl;
            f32x4 v = *(const f32x4*)&txp[w][rowl][fq * 4];
            f32x4 cx = *(const f32x4*)(ctxproj + (size_t)bL * INDIM +
                                       mel * 16 + fq * 4);
            *(f32x4*)(out0 + (size_t)(bL * NMEL + mel) * TMEL +
                      t * NFR + fq * 4) = v + cx;
        }
    }
}

// GEMM 3: ctxproj' = context @ Wp_ctx'^T + b_proj (f32 out, permuted cols).
// M=256(b) N=1280(mp) K=256.
__global__ __launch_bounds__(256) void k_gemm_ctx(
    const unsigned short* __restrict__ A,   // context bf16 [256][256]
    const unsigned short* __restrict__ Bw,  // Wp_ctx' bf16 [1280][256]
    const float* __restrict__ bproj,
    float* __restrict__ ctxout)             // [256][1280] f32 (permuted)
{
    __shared__ unsigned short As[3][4096], Bs[3][4096];   // 48KB
    f32x4 acc[4][4] = {};
    const int mblk = blockIdx.y * 128, nblk = blockIdx.x * 128;
    gemm_core4<ENC, ENC>(A, Bw, mblk, nblk, &As[0][0], &Bs[0][0], acc);
    const int lane = threadIdx.x & 63, w = threadIdx.x >> 6;
    const int wm = (w >> 1) * 64, wn = (w & 1) * 64;
    const int lr = lane & 15, q = lane >> 4;
    #pragma unroll
    for (int ni = 0; ni < 4; ++ni) {
        const int mp = nblk + wn + ni * 16 + lr;
        const int mel = mp >> 4, fr = mp & 15;
        const float bias = bproj[fr * NMEL + mel];
        #pragma unroll
        for (int mi = 0; mi < 4; ++mi) {
            const int b0 = mblk + wm + mi * 16 + q * 4;
            #pragma unroll
            for (int r = 0; r < 4; ++r)
                ctxout[(size_t)(b0 + r) * INDIM + mp] = acc[mi][ni][r] + bias;
        }
    }
}

// ---------------- per-step fused LSTM kernel (v9, best known: 9.3us/step) --
// 512 thr = 8 waves, wave -> gate g = w&3, m-half mh = w>>2; BK=128, 8 iters,
// 3 x 16KB buffers, 16-sub XOR swizzle, c + xg prefetched via global_load_lds,
// __expf activations, ONE merged barrier per iter:
//   vmcnt(4) -> lgkmcnt(0) -> s_barrier -> STAGE(it+2) -> compute(it)
__global__ __launch_bounds__(512) void k_step(
    const unsigned short* __restrict__ Whh,     // [4096][1024] bf16
    const unsigned short* __restrict__ xproj_t, // [256][4096] bf16
    const unsigned short* __restrict__ h_prev,  // [256][1024] bf16
    unsigned short* __restrict__ h_next,        // [256][1024] bf16
    float* __restrict__ c)                      // [256][1024] f32
{
    __shared__ unsigned short Abuf[3][8192];    // h 64r x 128k per buf (16KB x3)
    __shared__ unsigned short Bbuf[3][8192];    // Whh 64vr x 128k per buf (16KB x3)
    __shared__ unsigned short xg[4096];         // xproj tile [4][64][16] (8KB)
    __shared__ float cld[64][16];               // cell state tile (4KB)
    __shared__ float gates[4][64][17];          // 17.4KB, +1 pad
    const int tid = threadIdx.x, lane = tid & 63, w = tid >> 6;
    const int g = w & 3, mh = w >> 2;
    const int n0 = blockIdx.x * 16, m0 = blockIdx.y * 64;
    const int lr = lane & 15, q = lane >> 4;

    const int cc1 = tid, cc2 = tid + 512;
    const int r1 = cc1 >> 4, s1g = (cc1 & 15) ^ (r1 & 15);
    const int r2 = cc2 >> 4, s2g = (cc2 & 15) ^ (r2 & 15);
    const unsigned short* a1src = h_prev + (size_t)(m0 + r1) * RNN + s1g * 8;
    const unsigned short* a2src = h_prev + (size_t)(m0 + r2) * RNN + s2g * 8;
    const unsigned short* b1src = Whh +
        (size_t)((r1 >> 4) * RNN + n0 + (r1 & 15)) * RNN + s1g * 8;
    const unsigned short* b2src = Whh +
        (size_t)((r2 >> 4) * RNN + n0 + (r2 & 15)) * RNN + s2g * 8;
    const unsigned short* xsrc = xproj_t +
        (size_t)(m0 + ((tid >> 1) & 63)) * G4 + (tid >> 7) * RNN + n0 +
        (tid & 1) * 8;
    const float* csrc = c + (size_t)(m0 + (tid >> 2)) * RNN + n0 + (tid & 3) * 4;

#define STAGE(buf, k0) do {                                                    \
    __builtin_amdgcn_global_load_lds((const GAS unsigned int*)(a1src + (k0)),  \
        (LAS unsigned int*)&Abuf[buf][w * 512], 16, 0, 0);                     \
    __builtin_amdgcn_global_load_lds((const GAS unsigned int*)(a2src + (k0)),  \
        (LAS unsigned int*)&Abuf[buf][4096 + w * 512], 16, 0, 0);              \
    __builtin_amdgcn_global_load_lds((const GAS unsigned int*)(b1src + (k0)),  \
        (LAS unsigned int*)&Bbuf[buf][w * 512], 16, 0, 0);                     \
    __builtin_amdgcn_global_load_lds((const GAS unsigned int*)(b2src + (k0)),  \
        (LAS unsigned int*)&Bbuf[buf][4096 + w * 512], 16, 0, 0); } while (0)

    // oldest ops first: c (tail input), xg (epilogue input)
    if (w < 4)
        __builtin_amdgcn_global_load_lds((const GAS unsigned int*)csrc,
            (LAS unsigned int*)&cld[w * 16][0], 16, 0, 0);
    __builtin_amdgcn_global_load_lds((const GAS unsigned int*)xsrc,
        (LAS unsigned int*)&xg[w * 512], 16, 0, 0);
    STAGE(0, 0); STAGE(1, 128);     // 2-tile prologue

    f32x4 acc[2] = {};
    #pragma unroll
    for (int it = 0; it < 8; ++it) {
        if (it <= 6) asm volatile("s_waitcnt vmcnt(4)" ::: "memory");
        else         asm volatile("s_waitcnt vmcnt(0)" ::: "memory");
        asm volatile("s_waitcnt lgkmcnt(0)" ::: "memory");  // my it-1 reads done
        asm volatile("s_barrier" ::: "memory");
        __builtin_amdgcn_sched_barrier(0);
        if (it <= 5) STAGE((it + 2) % 3, (it + 2) * 128);   // safe post-barrier
        const unsigned short* Ab = Abuf[it % 3];
        const unsigned short* Bb = Bbuf[it % 3];
        #pragma unroll
        for (int ks = 0; ks < 4; ++ks) {
            const int j = ((ks * 4 + q) ^ lr) * 8;   // swizzled 16B sub-chunk
            bf16x8 a0 = *(const bf16x8*)(Ab + (mh * 32 + lr) * 128 + j);
            bf16x8 a1 = *(const bf16x8*)(Ab + (mh * 32 + 16 + lr) * 128 + j);
            bf16x8 bv = *(const bf16x8*)(Bb + (g * 16 + lr) * 128 + j);
            acc[0] = __builtin_amdgcn_mfma_f32_16x16x32_bf16(a0, bv, acc[0], 0, 0, 0);
            acc[1] = __builtin_amdgcn_mfma_f32_16x16x32_bf16(a1, bv, acc[1], 0, 0, 0);
        }
    }

    // epilogue: gates = acc + xg (wave-exclusive (g, mh) rows)
    #pragma unroll
    for (int mi = 0; mi < 2; ++mi)
        #pragma unroll
        for (int r = 0; r < 4; ++r) {
            const int row = mh * 32 + mi * 16 + q * 4 + r;
            gates[g][row][lr] = acc[mi][r] +
                bf2f(xg[(g * 64 + row) * 16 + lr]);
        }
    __syncthreads();

    // LSTM tail: 1024 elements (64x16), 2 per thread; c from LDS prefetch
    #pragma unroll
    for (int q2 = 0; q2 < 2; ++q2) {
        const int e = tid + q2 * 512;
        const int row = e >> 4, col = e & 15;
        const int b = m0 + row, j = n0 + col;
        const float xi = gates[0][row][col];
        const float xf = gates[1][row][col];
        const float xgt = gates[2][row][col];
        const float xo = gates[3][row][col];
        const float si = fsig(xi);
        const float sf = fsig(xf);
        const float so = fsig(xo);
        const float cp = cld[row][col];
        const float cn = sf * cp + si * ftanh(xgt);
        const float hn = so * ftanh(cn);
        c[(size_t)b * RNN + j] = cn;
        h_next[(size_t)b * RNN + j] = f2bf(hn);
    }
#undef STAGE
}

// gate[b*50+t] = gatectx[b] + h_all[t+1][b]·w_gate[0:1024] ; one wave per row
__global__ void k_gate(const unsigned short* __restrict__ h,  // [12800][1024]
                       const float* __restrict__ wgate,
                       const float* __restrict__ gctx,
                       float* __restrict__ out1) {
    const int gw = (blockIdx.x * blockDim.x + threadIdx.x) >> 6;
    const int lane = threadIdx.x & 63;
    if (gw >= MROWS) return;
    const unsigned short* hr = h + (size_t)gw * RNN + lane * 16;
    const float* wr = wgate + lane * 16;
    float acc = 0.f;
    #pragma unroll
    for (int j = 0; j < 16; ++j) acc += bf2f(hr[j]) * wr[j];
    for (int off = 32; off; off >>= 1) acc += __shfl_down(acc, off);
    if (lane == 0) {
        const int t = gw >> 8, b = gw & 255;
        out1[b * TT + t] = acc + gctx[b];
    }
}

// ---------------- workspace layout (all offsets 1KB-aligned) ----------------
static const size_t OFF_WIH   = 0;                                    // 10.5 MB
static const size_t OFF_WHH   = OFF_WIH   + (size_t)G4 * INDIM * 2;   // 8 MB
static const size_t OFF_WPH   = OFF_WHH   + (size_t)G4 * RNN * 2;     // 2.6 MB
static const size_t OFF_WPC   = OFF_WPH   + (size_t)INDIM * RNN * 2;  // 0.65 MB
static const size_t OFF_CTXB  = OFF_WPC   + (size_t)INDIM * ENC * 2;  // 128 KB
static const size_t OFF_FRM   = OFF_CTXB  + (size_t)BB * ENC * 2;     // 32.8 MB
static const size_t OFF_XPROJ = OFF_FRM   + (size_t)MROWS * INDIM * 2;// 104.9 MB
static const size_t OFF_HALL  = OFF_XPROJ + (size_t)MROWS * G4 * 2;   // 26.7 MB
static const size_t OFF_C     = OFF_HALL  + (size_t)(TT + 1) * BB * RNN * 2;
static const size_t OFF_CTX   = OFF_C     + (size_t)BB * RNN * 4;
static const size_t OFF_GCTX  = OFF_CTX   + (size_t)BB * INDIM * 4;

extern "C" void kernel_launch(void* const* d_in, const int* in_sizes, int n_in,
                              void* d_out, int out_size, void* d_ws, size_t ws_size,
                              hipStream_t stream) {
    const float* context = (const float*)d_in[0];
    const float* target  = (const float*)d_in[1];
    const float* W_ih    = (const float*)d_in[2];
    const float* b_ih    = (const float*)d_in[3];
    const float* W_hh    = (const float*)d_in[4];
    const float* b_hh    = (const float*)d_in[5];
    const float* W_proj  = (const float*)d_in[6];
    const float* b_proj  = (const float*)d_in[7];
    const float* W_gate  = (const float*)d_in[8];
    const float* b_gate  = (const float*)d_in[9];
    float* out = (float*)d_out;
    char* ws = (char*)d_ws;

    unsigned short* wih_bf  = (unsigned short*)(ws + OFF_WIH);
    unsigned short* whh_bf  = (unsigned short*)(ws + OFF_WHH);
    unsigned short* wph_bf  = (unsigned short*)(ws + OFF_WPH);
    unsigned short* wpc_bf  = (unsigned short*)(ws + OFF_WPC);
    unsigned short* ctx_bf  = (unsigned short*)(ws + OFF_CTXB);
    unsigned short* frames  = (unsigned short*)(ws + OFF_FRM);
    unsigned short* xproj   = (unsigned short*)(ws + OFF_XPROJ);
    unsigned short* h_all   = (unsigned short*)(ws + OFF_HALL);
    float*          c_buf   = (float*)(ws + OFF_C);
    float*          ctxproj = (float*)(ws + OFF_CTX);
    float*          gctx    = (float*)(ws + OFF_GCTX);

    // per-call init (harness does not re-zero ws between replays)
    hipMemsetAsync(h_all, 0, (size_t)BB * RNN * 2, stream);   // h0 slot
    hipMemsetAsync(c_buf, 0, (size_t)BB * RNN * 4, stream);   // c0

    k_f32_to_bf16<<<2048, 256, 0, stream>>>(W_ih, wih_bf, G4 * INDIM / 4);
    k_f32_to_bf16<<<2048, 256, 0, stream>>>(W_hh, whh_bf, G4 * RNN / 4);
    k_conv_wph<<<2048, 256, 0, stream>>>(W_proj, wph_bf);
    k_conv_wpc<<<320, 256, 0, stream>>>(W_proj, wpc_bf);
    k_f32_to_bf16<<<64, 256, 0, stream>>>(context, ctx_bf, BB * ENC / 4);
    k_frames<<<MROWS, 128, 0, stream>>>(target, frames);
    k_gatectx<<<1, 256, 0, stream>>>(context, W_gate, b_gate, gctx);

    k_gemm_ctx<<<dim3(INDIM / 128, BB / 128), 256, 0, stream>>>(
        ctx_bf, wpc_bf, b_proj, ctxproj);

    k_gemm_xproj<<<dim3(G4 / 128, MROWS / 128), 256, 0, stream>>>(
        frames, wih_bf, b_ih, b_hh, xproj);

    for (int t = 0; t < TT; ++t) {
        k_step<<<dim3(64, 4), 512, 0, stream>>>(
            whh_bf, xproj + (size_t)t * BB * G4,
            h_all + (size_t)t * BB * RNN,
            h_all + (size_t)(t + 1) * BB * RNN, c_buf);
    }

    k_gemm_mel<<<dim3(INDIM / 128, MROWS / 128), 256, 0, stream>>>(
        h_all + (size_t)BB * RNN, wph_bf, ctxproj, out);
    k_gate<<<MROWS / 4, 256, 0, stream>>>(h_all + (size_t)BB * RNN, W_gate,
                                          gctx, out + (size_t)BB * NMEL * TMEL);
}

// Round 19
// 701.717 us; speedup vs baseline: 1.2276x; 1.2276x over previous
//
#include <hip/hip_runtime.h>
#include <hip/hip_bf16.h>
#include <math.h>

// Problem constants
#define BB     256
#define NMEL   80
#define TMEL   800
#define NFR    16          // frames per step
#define TT     50          // decoder steps
#define RNN    1024
#define ENC    256
#define INDIM  1280        // RNN + ENC == MEL_DIM
#define G4     4096        // 4*RNN
#define MROWS  (TT*BB)     // 12800

typedef __attribute__((ext_vector_type(8))) short bf16x8;
typedef __attribute__((ext_vector_type(4))) float f32x4;

#define GAS __attribute__((address_space(1)))
#define LAS __attribute__((address_space(3)))

__device__ __forceinline__ unsigned short f2bf(float f) {
    unsigned int u = __float_as_uint(f);
    u += 0x7FFFu + ((u >> 16) & 1u);     // round-to-nearest-even
    return (unsigned short)(u >> 16);
}
__device__ __forceinline__ float bf2f(unsigned short s) {
    return __uint_as_float(((unsigned int)s) << 16);
}
__device__ __forceinline__ float fsig(float x) {      // inf-safe fast sigmoid
    return 1.f / (1.f + __expf(-x));
}
__device__ __forceinline__ float ftanh(float x) {     // tanh = 2*sig(2x)-1
    return 2.f / (1.f + __expf(-2.f * x)) - 1.f;
}

// ---------------- prep kernels ----------------

// vectorized f32 -> bf16 (n4 = n/4 16B-chunks)
__global__ void k_f32_to_bf16(const float* __restrict__ src,
                              unsigned short* __restrict__ dst, int n4) {
    for (int i = blockIdx.x * blockDim.x + threadIdx.x; i < n4;
         i += gridDim.x * blockDim.x) {
        f32x4 v = *(const f32x4*)(src + (size_t)i * 4);
        unsigned long long p = (unsigned long long)f2bf(v[0]) |
                               ((unsigned long long)f2bf(v[1]) << 16) |
                               ((unsigned long long)f2bf(v[2]) << 32) |
                               ((unsigned long long)f2bf(v[3]) << 48);
        *(unsigned long long*)(dst + (size_t)i * 4) = p;
    }
}

// W_proj[:, 0:1024] -> bf16, N-permuted: dst row m' = mel*16+fr comes from
// W_proj row m = fr*80+mel. 4-wide chunks.
__global__ void k_conv_wph(const float* __restrict__ wproj,
                           unsigned short* __restrict__ dst) {
    const int n4 = INDIM * RNN / 4;
    for (int i = blockIdx.x * blockDim.x + threadIdx.x; i < n4;
         i += gridDim.x * blockDim.x) {
        int mp = i >> 8, kc = (i & 255) * 4;
        int mel = mp >> 4, fr = mp & 15;
        f32x4 v = *(const f32x4*)(wproj + (size_t)(fr * NMEL + mel) * INDIM + kc);
        unsigned long long p = (unsigned long long)f2bf(v[0]) |
                               ((unsigned long long)f2bf(v[1]) << 16) |
                               ((unsigned long long)f2bf(v[2]) << 32) |
                               ((unsigned long long)f2bf(v[3]) << 48);
        *(unsigned long long*)(dst + (size_t)i * 4) = p;
    }
}

// W_proj[:, 1024:1280] -> bf16 [1280][256], rows permuted m' = mel*16+fr.
__global__ void k_conv_wpc(const float* __restrict__ wproj,
                           unsigned short* __restrict__ dst) {
    const int n4 = INDIM * ENC / 4;                 // 81920 chunks
    for (int i = blockIdx.x * blockDim.x + threadIdx.x; i < n4;
         i += gridDim.x * blockDim.x) {
        int mp = i >> 6, kc = (i & 63) * 4;
        int mel = mp >> 4, fr = mp & 15;
        f32x4 v = *(const f32x4*)(wproj + (size_t)(fr * NMEL + mel) * INDIM +
                                  RNN + kc);
        unsigned long long p = (unsigned long long)f2bf(v[0]) |
                               ((unsigned long long)f2bf(v[1]) << 16) |
                               ((unsigned long long)f2bf(v[2]) << 32) |
                               ((unsigned long long)f2bf(v[3]) << 48);
        *(unsigned long long*)(dst + (size_t)i * 4) = p;
    }
}

// teacher-forced inputs via LDS transpose tile: WG per (t,b).
// frames[t][b][k] = (t==0)?0:target[b][k%80][t*16+k/80]
__global__ __launch_bounds__(128) void k_frames(const float* __restrict__ target,
                                                unsigned short* __restrict__ frames) {
    const int wg = blockIdx.x;              // 0..12799
    const int t = wg >> 8, b = wg & 255;
    unsigned short* dst = frames + ((size_t)t * BB + b) * INDIM;
    if (t == 0) {
        for (int i = threadIdx.x; i < INDIM / 8; i += 128)
            *(f32x4*)(dst + i * 8) = (f32x4){0.f, 0.f, 0.f, 0.f};
        return;
    }
    __shared__ float ld[NMEL][17];
    for (int i = threadIdx.x; i < 320; i += 128) {    // 80 mel x 4 f32x4
        const int mel = i >> 2, fq = i & 3;
        f32x4 v = *(const f32x4*)(target + ((size_t)b * NMEL + mel) * TMEL +
                                  t * NFR + fq * 4);
        #pragma unroll
        for (int j = 0; j < 4; ++j) ld[mel][fq * 4 + j] = v[j];
    }
    __syncthreads();
    for (int i = threadIdx.x; i < 160; i += 128) {    // 160 x 8-short chunks
        unsigned long long p0 = 0, p1 = 0;
        #pragma unroll
        for (int j = 0; j < 4; ++j) {
            const int k = i * 8 + j;
            p0 |= (unsigned long long)f2bf(ld[k % 80][k / 80]) << (16 * j);
        }
        #pragma unroll
        for (int j = 0; j < 4; ++j) {
            const int k = i * 8 + 4 + j;
            p1 |= (unsigned long long)f2bf(ld[k % 80][k / 80]) << (16 * j);
        }
        *(unsigned long long*)(dst + i * 8) = p0;
        *(unsigned long long*)(dst + i * 8 + 4) = p1;
    }
}

// gatectx[b] = b_gate + context[b]·W_gate[0][1024:1280]
__global__ void k_gatectx(const float* __restrict__ context,
                          const float* __restrict__ wgate,
                          const float* __restrict__ bgate,
                          float* __restrict__ gctx) {
    int b = blockIdx.x * blockDim.x + threadIdx.x;
    if (b >= BB) return;
    float acc = bgate[0];
    const float* cb = context + b * ENC;
    for (int e = 0; e < ENC; ++e) acc += cb[e] * wgate[RNN + e];
    gctx[b] = acc;
}

// ---------------- GEMM core v2 (proven: 169us xproj, 0 conflicts, 2 WG/CU) -
// 128x128 WG tile, BK=64, 512 thr / 8 waves (wave -> 64x32 output).
// Both-sides 8-sub XOR swizzle; 2-buffer counted-vmcnt pipeline.
template<int STRIDE, int KDIM>
__device__ __forceinline__ void gemm_core2(const unsigned short* __restrict__ A,
                                           const unsigned short* __restrict__ Bw,
                                           int mblk, int nblk,
                                           unsigned short* As,   // [2][8192]
                                           unsigned short* Bs,   // [2][8192]
                                           f32x4 acc[4][2]) {
    const int tid = threadIdx.x, lane = tid & 63, w = tid >> 6;
    const int lr = lane & 15, q = lane >> 4;
    const int wm = (w >> 2) * 64, wn = (w & 3) * 32;
    const int cc1 = tid, cc2 = tid + 512;
    const int r1 = cc1 >> 3, s1 = ((cc1 & 7) ^ (r1 & 7)) * 8;
    const int r2 = cc2 >> 3, s2 = ((cc2 & 7) ^ (r2 & 7)) * 8;
    const unsigned short* a1p = A + (size_t)(mblk + r1) * STRIDE + s1;
    const unsigned short* a2p = A + (size_t)(mblk + r2) * STRIDE + s2;
    const unsigned short* b1p = Bw + (size_t)(nblk + r1) * STRIDE + s1;
    const unsigned short* b2p = Bw + (size_t)(nblk + r2) * STRIDE + s2;

#define GSTAGE(buf, k0) do {                                                   \
    __builtin_amdgcn_global_load_lds((const GAS unsigned int*)(a1p + (k0)),    \
        (LAS unsigned int*)(As + (buf) * 8192 + w * 512), 16, 0, 0);           \
    __builtin_amdgcn_global_load_lds((const GAS unsigned int*)(a2p + (k0)),    \
        (LAS unsigned int*)(As + (buf) * 8192 + 4096 + w * 512), 16, 0, 0);    \
    __builtin_amdgcn_global_load_lds((const GAS unsigned int*)(b1p + (k0)),    \
        (LAS unsigned int*)(Bs + (buf) * 8192 + w * 512), 16, 0, 0);           \
    __builtin_amdgcn_global_load_lds((const GAS unsigned int*)(b2p + (k0)),    \
        (LAS unsigned int*)(Bs + (buf) * 8192 + 4096 + w * 512), 16, 0, 0); } while (0)

    constexpr int NIT = KDIM / 64;
    GSTAGE(0, 0);
    #pragma unroll 4
    for (int it = 0; it < NIT; ++it) {
        if (it < NIT - 1) {
            GSTAGE((it + 1) & 1, (it + 1) * 64);
            asm volatile("s_waitcnt vmcnt(4)" ::: "memory");
        } else {
            asm volatile("s_waitcnt vmcnt(0)" ::: "memory");
        }
        asm volatile("s_barrier" ::: "memory");
        __builtin_amdgcn_sched_barrier(0);
        const unsigned short* Ab = As + (it & 1) * 8192;
        const unsigned short* Bb = Bs + (it & 1) * 8192;
        #pragma unroll
        for (int ks = 0; ks < 2; ++ks) {
            const int j = (((ks * 4 + q) ^ (lr & 7)) * 8);  // swizzled 16B sub
            bf16x8 af[4], bv[2];
            #pragma unroll
            for (int mi = 0; mi < 4; ++mi)
                af[mi] = *(const bf16x8*)(Ab + (wm + mi * 16 + lr) * 64 + j);
            #pragma unroll
            for (int ni = 0; ni < 2; ++ni)
                bv[ni] = *(const bf16x8*)(Bb + (wn + ni * 16 + lr) * 64 + j);
            #pragma unroll
            for (int mi = 0; mi < 4; ++mi)
                #pragma unroll
                for (int ni = 0; ni < 2; ++ni)
                    acc[mi][ni] = __builtin_amdgcn_mfma_f32_16x16x32_bf16(
                        af[mi], bv[ni], acc[mi][ni], 0, 0, 0);
        }
        asm volatile("s_waitcnt lgkmcnt(0)" ::: "memory");
        __builtin_amdgcn_sched_barrier(0);
        asm volatile("s_barrier" ::: "memory");
    }
#undef GSTAGE
}

// GEMM 1: xproj = frames @ W_ih^T + b_ih + b_hh (bf16 out). M=12800 N=4096 K=1280
__global__ __launch_bounds__(512) void k_gemm_xproj(
    const unsigned short* __restrict__ A,   // [12800][1280]
    const unsigned short* __restrict__ Bw,  // [4096][1280]
    const float* __restrict__ b_ih, const float* __restrict__ b_hh,
    unsigned short* __restrict__ Cout)      // [12800][4096]
{
    __shared__ unsigned short As[2][8192], Bs[2][8192];   // 64KB
    f32x4 acc[4][2] = {};
    const int mblk = blockIdx.y * 128, nblk = blockIdx.x * 128;
    gemm_core2<INDIM, INDIM>(A, Bw, mblk, nblk, &As[0][0], &Bs[0][0], acc);
    const int lane = threadIdx.x & 63, w = threadIdx.x >> 6;
    const int wm = (w >> 2) * 64, wn = (w & 3) * 32;
    const int lr = lane & 15, q = lane >> 4;
    #pragma unroll
    for (int ni = 0; ni < 2; ++ni) {
        const int col = nblk + wn + ni * 16 + lr;
        const float bias = b_ih[col] + b_hh[col];
        #pragma unroll
        for (int mi = 0; mi < 4; ++mi) {
            const int row0 = mblk + wm + mi * 16 + q * 4;
            #pragma unroll
            for (int r = 0; r < 4; ++r)
                Cout[(size_t)(row0 + r) * G4 + col] = f2bf(acc[mi][ni][r] + bias);
        }
    }
}

// GEMM 2: mel = h_all[1:] @ Wp'^T + ctxproj'. txp is wave-private -> no
// __syncthreads in the epilogue (same-wave LDS deps ordered by lgkmcnt).
__global__ __launch_bounds__(512) void k_gemm_mel(
    const unsigned short* __restrict__ A,   // [12800][1024]
    const unsigned short* __restrict__ Bw,  // Wp' [1280][1024] (permuted)
    const float* __restrict__ ctxproj,      // [256][1280] (permuted)
    float* __restrict__ out0)               // [256][80][800]
{
    __shared__ unsigned short As[2][8192], Bs[2][8192];   // 64KB
    __shared__ float txp[8][16][20];        // per-wave transpose (10.25KB)
    f32x4 acc[4][2] = {};
    const int mblk = blockIdx.y * 128, nblk = blockIdx.x * 128;
    gemm_core2<RNN, RNN>(A, Bw, mblk, nblk, &As[0][0], &Bs[0][0], acc);
    const int lane = threadIdx.x & 63, w = threadIdx.x >> 6;
    const int wm = (w >> 2) * 64, wn = (w & 3) * 32;
    const int lr = lane & 15, q = lane >> 4;
    const int rbase = q * 4;
    const int rowl = lane & 15, fq = lane >> 4;   // readback roles
    #pragma unroll
    for (int mi = 0; mi < 4; ++mi) {
        const int row0 = mblk + wm + mi * 16;     // 16 rows: same t, b0..b0+15
        const int t = row0 >> 8, b0 = row0 & 255;
        #pragma unroll
        for (int ni = 0; ni < 2; ++ni) {
            const int colbase = nblk + wn + ni * 16;  // one mel, fr 0..15
            const int mel = colbase >> 4;
            #pragma unroll
            for (int r = 0; r < 4; ++r)
                txp[w][rbase + r][lr] = acc[mi][ni][r];
            const int bL = b0 + rowl;
            f32x4 v = *(const f32x4*)&txp[w][rowl][fq * 4];
            f32x4 cx = *(const f32x4*)(ctxproj + (size_t)bL * INDIM +
                                       mel * 16 + fq * 4);
            *(f32x4*)(out0 + (size_t)(bL * NMEL + mel) * TMEL +
                      t * NFR + fq * 4) = v + cx;
        }
    }
}

// GEMM 3: ctxproj' = context @ Wp_ctx'^T + b_proj (f32 out, permuted cols).
// M=256(b) N=1280(mp) K=256.
__global__ __launch_bounds__(512) void k_gemm_ctx(
    const unsigned short* __restrict__ A,   // context bf16 [256][256]
    const unsigned short* __restrict__ Bw,  // Wp_ctx' bf16 [1280][256]
    const float* __restrict__ bproj,
    float* __restrict__ ctxout)             // [256][1280] f32 (permuted)
{
    __shared__ unsigned short As[2][8192], Bs[2][8192];   // 64KB
    f32x4 acc[4][2] = {};
    const int mblk = blockIdx.y * 128, nblk = blockIdx.x * 128;
    gemm_core2<ENC, ENC>(A, Bw, mblk, nblk, &As[0][0], &Bs[0][0], acc);
    const int lane = threadIdx.x & 63, w = threadIdx.x >> 6;
    const int wm = (w >> 2) * 64, wn = (w & 3) * 32;
    const int lr = lane & 15, q = lane >> 4;
    #pragma unroll
    for (int ni = 0; ni < 2; ++ni) {
        const int mp = nblk + wn + ni * 16 + lr;
        const int mel = mp >> 4, fr = mp & 15;
        const float bias = bproj[fr * NMEL + mel];
        #pragma unroll
        for (int mi = 0; mi < 4; ++mi) {
            const int b0 = mblk + wm + mi * 16 + q * 4;
            #pragma unroll
            for (int r = 0; r < 4; ++r)
                ctxout[(size_t)(b0 + r) * INDIM + mp] = acc[mi][ni][r] + bias;
        }
    }
}

// ---------------- per-step fused LSTM kernel (v11 = v9 + 3-deep prefetch) --
// 512 thr = 8 waves, wave -> gate g = w&3, m-half mh = w>>2; BK=128, 8 iters,
// FOUR 16KB buffers (LDS 157KB, 1 WG/CU unchanged), 16-sub XOR swizzle,
// c + xg prefetched via global_load_lds, __expf activations, ONE merged
// barrier per iter. 3-deep ladder: prologue stages {0,1,2}; per iter
//   vmcnt(8) [stages it+1,it+2 in flight] -> lgkmcnt(0) -> s_barrier ->
//   STAGE(it+3) -> compute(it);  it=6: vmcnt(4), it=7: vmcnt(0).
// Buffer reuse: buffer (it+3)&3 was last read at it-1; lgkm+barrier prove
// all waves' reads retired before the overwrite issues (same v9 proof).
__global__ __launch_bounds__(512) void k_step(
    const unsigned short* __restrict__ Whh,     // [4096][1024] bf16
    const unsigned short* __restrict__ xproj_t, // [256][4096] bf16
    const unsigned short* __restrict__ h_prev,  // [256][1024] bf16
    unsigned short* __restrict__ h_next,        // [256][1024] bf16
    float* __restrict__ c)                      // [256][1024] f32
{
    __shared__ unsigned short Abuf[4][8192];    // h 64r x 128k per buf (16KB x4)
    __shared__ unsigned short Bbuf[4][8192];    // Whh 64vr x 128k (16KB x4)
    __shared__ unsigned short xg[4096];         // xproj tile [4][64][16] (8KB)
    __shared__ float cld[64][16];               // cell state tile (4KB)
    __shared__ float gates[4][64][17];          // 17.4KB  => 157.4KB total
    const int tid = threadIdx.x, lane = tid & 63, w = tid >> 6;
    const int g = w & 3, mh = w >> 2;
    const int n0 = blockIdx.x * 16, m0 = blockIdx.y * 64;
    const int lr = lane & 15, q = lane >> 4;

    const int cc1 = tid, cc2 = tid + 512;
    const int r1 = cc1 >> 4, s1g = (cc1 & 15) ^ (r1 & 15);
    const int r2 = cc2 >> 4, s2g = (cc2 & 15) ^ (r2 & 15);
    const unsigned short* a1src = h_prev + (size_t)(m0 + r1) * RNN + s1g * 8;
    const unsigned short* a2src = h_prev + (size_t)(m0 + r2) * RNN + s2g * 8;
    const unsigned short* b1src = Whh +
        (size_t)((r1 >> 4) * RNN + n0 + (r1 & 15)) * RNN + s1g * 8;
    const unsigned short* b2src = Whh +
        (size_t)((r2 >> 4) * RNN + n0 + (r2 & 15)) * RNN + s2g * 8;
    const unsigned short* xsrc = xproj_t +
        (size_t)(m0 + ((tid >> 1) & 63)) * G4 + (tid >> 7) * RNN + n0 +
        (tid & 1) * 8;
    const float* csrc = c + (size_t)(m0 + (tid >> 2)) * RNN + n0 + (tid & 3) * 4;

#define STAGE(buf, k0) do {                                                    \
    __builtin_amdgcn_global_load_lds((const GAS unsigned int*)(a1src + (k0)),  \
        (LAS unsigned int*)&Abuf[buf][w * 512], 16, 0, 0);                     \
    __builtin_amdgcn_global_load_lds((const GAS unsigned int*)(a2src + (k0)),  \
        (LAS unsigned int*)&Abuf[buf][4096 + w * 512], 16, 0, 0);              \
    __builtin_amdgcn_global_load_lds((const GAS unsigned int*)(b1src + (k0)),  \
        (LAS unsigned int*)&Bbuf[buf][w * 512], 16, 0, 0);                     \
    __builtin_amdgcn_global_load_lds((const GAS unsigned int*)(b2src + (k0)),  \
        (LAS unsigned int*)&Bbuf[buf][4096 + w * 512], 16, 0, 0); } while (0)

    // oldest ops first: c (tail input), xg (epilogue input)
    if (w < 4)
        __builtin_amdgcn_global_load_lds((const GAS unsigned int*)csrc,
            (LAS unsigned int*)&cld[w * 16][0], 16, 0, 0);
    __builtin_amdgcn_global_load_lds((const GAS unsigned int*)xsrc,
        (LAS unsigned int*)&xg[w * 512], 16, 0, 0);
    STAGE(0, 0); STAGE(1, 128); STAGE(2, 256);   // 3-deep prologue

    f32x4 acc[2] = {};
    #pragma unroll
    for (int it = 0; it < 8; ++it) {
        // wait for stage(it); stages it+1, it+2 (8 ops) may stay in flight
        if (it <= 5)      asm volatile("s_waitcnt vmcnt(8)" ::: "memory");
        else if (it == 6) asm volatile("s_waitcnt vmcnt(4)" ::: "memory");
        else              asm volatile("s_waitcnt vmcnt(0)" ::: "memory");
        asm volatile("s_waitcnt lgkmcnt(0)" ::: "memory");  // my it-1 reads done
        asm volatile("s_barrier" ::: "memory");
        __builtin_amdgcn_sched_barrier(0);
        if (it <= 4) STAGE((it + 3) & 3, (it + 3) * 128);   // safe post-barrier
        const unsigned short* Ab = Abuf[it & 3];
        const unsigned short* Bb = Bbuf[it & 3];
        #pragma unroll
        for (int ks = 0; ks < 4; ++ks) {
            const int j = ((ks * 4 + q) ^ lr) * 8;   // swizzled 16B sub-chunk
            bf16x8 a0 = *(const bf16x8*)(Ab + (mh * 32 + lr) * 128 + j);
            bf16x8 a1 = *(const bf16x8*)(Ab + (mh * 32 + 16 + lr) * 128 + j);
            bf16x8 bv = *(const bf16x8*)(Bb + (g * 16 + lr) * 128 + j);
            acc[0] = __builtin_amdgcn_mfma_f32_16x16x32_bf16(a0, bv, acc[0], 0, 0, 0);
            acc[1] = __builtin_amdgcn_mfma_f32_16x16x32_bf16(a1, bv, acc[1], 0, 0, 0);
        }
    }

    // epilogue: gates = acc + xg (wave-exclusive (g, mh) rows)
    #pragma unroll
    for (int mi = 0; mi < 2; ++mi)
        #pragma unroll
        for (int r = 0; r < 4; ++r) {
            const int row = mh * 32 + mi * 16 + q * 4 + r;
            gates[g][row][lr] = acc[mi][r] +
                bf2f(xg[(g * 64 + row) * 16 + lr]);
        }
    __syncthreads();

    // LSTM tail: 1024 elements (64x16), 2 per thread; c from LDS prefetch
    #pragma unroll
    for (int q2 = 0; q2 < 2; ++q2) {
        const int e = tid + q2 * 512;
        const int row = e >> 4, col = e & 15;
        const int b = m0 + row, j = n0 + col;
        const float xi = gates[0][row][col];
        const float xf = gates[1][row][col];
        const float xgt = gates[2][row][col];
        const float xo = gates[3][row][col];
        const float si = fsig(xi);
        const float sf = fsig(xf);
        const float so = fsig(xo);
        const float cp = cld[row][col];
        const float cn = sf * cp + si * ftanh(xgt);
        const float hn = so * ftanh(cn);
        c[(size_t)b * RNN + j] = cn;
        h_next[(size_t)b * RNN + j] = f2bf(hn);
    }
#undef STAGE
}

// gate[b*50+t] = gatectx[b] + h_all[t+1][b]·w_gate[0:1024] ; one wave per row
__global__ void k_gate(const unsigned short* __restrict__ h,  // [12800][1024]
                       const float* __restrict__ wgate,
                       const float* __restrict__ gctx,
                       float* __restrict__ out1) {
    const int gw = (blockIdx.x * blockDim.x + threadIdx.x) >> 6;
    const int lane = threadIdx.x & 63;
    if (gw >= MROWS) return;
    const unsigned short* hr = h + (size_t)gw * RNN + lane * 16;
    const float* wr = wgate + lane * 16;
    float acc = 0.f;
    #pragma unroll
    for (int j = 0; j < 16; ++j) acc += bf2f(hr[j]) * wr[j];
    for (int off = 32; off; off >>= 1) acc += __shfl_down(acc, off);
    if (lane == 0) {
        const int t = gw >> 8, b = gw & 255;
        out1[b * TT + t] = acc + gctx[b];
    }
}

// ---------------- workspace layout (all offsets 1KB-aligned) ----------------
static const size_t OFF_WIH   = 0;                                    // 10.5 MB
static const size_t OFF_WHH   = OFF_WIH   + (size_t)G4 * INDIM * 2;   // 8 MB
static const size_t OFF_WPH   = OFF_WHH   + (size_t)G4 * RNN * 2;     // 2.6 MB
static const size_t OFF_WPC   = OFF_WPH   + (size_t)INDIM * RNN * 2;  // 0.65 MB
static const size_t OFF_CTXB  = OFF_WPC   + (size_t)INDIM * ENC * 2;  // 128 KB
static const size_t OFF_FRM   = OFF_CTXB  + (size_t)BB * ENC * 2;     // 32.8 MB
static const size_t OFF_XPROJ = OFF_FRM   + (size_t)MROWS * INDIM * 2;// 104.9 MB
static const size_t OFF_HALL  = OFF_XPROJ + (size_t)MROWS * G4 * 2;   // 26.7 MB
static const size_t OFF_C     = OFF_HALL  + (size_t)(TT + 1) * BB * RNN * 2;
static const size_t OFF_CTX   = OFF_C     + (size_t)BB * RNN * 4;
static const size_t OFF_GCTX  = OFF_CTX   + (size_t)BB * INDIM * 4;

extern "C" void kernel_launch(void* const* d_in, const int* in_sizes, int n_in,
                              void* d_out, int out_size, void* d_ws, size_t ws_size,
                              hipStream_t stream) {
    const float* context = (const float*)d_in[0];
    const float* target  = (const float*)d_in[1];
    const float* W_ih    = (const float*)d_in[2];
    const float* b_ih    = (const float*)d_in[3];
    const float* W_hh    = (const float*)d_in[4];
    const float* b_hh    = (const float*)d_in[5];
    const float* W_proj  = (const float*)d_in[6];
    const float* b_proj  = (const float*)d_in[7];
    const float* W_gate  = (const float*)d_in[8];
    const float* b_gate  = (const float*)d_in[9];
    float* out = (float*)d_out;
    char* ws = (char*)d_ws;

    unsigned short* wih_bf  = (unsigned short*)(ws + OFF_WIH);
    unsigned short* whh_bf  = (unsigned short*)(ws + OFF_WHH);
    unsigned short* wph_bf  = (unsigned short*)(ws + OFF_WPH);
    unsigned short* wpc_bf  = (unsigned short*)(ws + OFF_WPC);
    unsigned short* ctx_bf  = (unsigned short*)(ws + OFF_CTXB);
    unsigned short* frames  = (unsigned short*)(ws + OFF_FRM);
    unsigned short* xproj   = (unsigned short*)(ws + OFF_XPROJ);
    unsigned short* h_all   = (unsigned short*)(ws + OFF_HALL);
    float*          c_buf   = (float*)(ws + OFF_C);
    float*          ctxproj = (float*)(ws + OFF_CTX);
    float*          gctx    = (float*)(ws + OFF_GCTX);

    // per-call init (harness does not re-zero ws between replays)
    hipMemsetAsync(h_all, 0, (size_t)BB * RNN * 2, stream);   // h0 slot
    hipMemsetAsync(c_buf, 0, (size_t)BB * RNN * 4, stream);   // c0

    k_f32_to_bf16<<<2048, 256, 0, stream>>>(W_ih, wih_bf, G4 * INDIM / 4);
    k_f32_to_bf16<<<2048, 256, 0, stream>>>(W_hh, whh_bf, G4 * RNN / 4);
    k_conv_wph<<<2048, 256, 0, stream>>>(W_proj, wph_bf);
    k_conv_wpc<<<320, 256, 0, stream>>>(W_proj, wpc_bf);
    k_f32_to_bf16<<<64, 256, 0, stream>>>(context, ctx_bf, BB * ENC / 4);
    k_frames<<<MROWS, 128, 0, stream>>>(target, frames);
    k_gatectx<<<1, 256, 0, stream>>>(context, W_gate, b_gate, gctx);

    k_gemm_ctx<<<dim3(INDIM / 128, BB / 128), 512, 0, stream>>>(
        ctx_bf, wpc_bf, b_proj, ctxproj);

    k_gemm_xproj<<<dim3(G4 / 128, MROWS / 128), 512, 0, stream>>>(
        frames, wih_bf, b_ih, b_hh, xproj);

    for (int t = 0; t < TT; ++t) {
        k_step<<<dim3(64, 4), 512, 0, stream>>>(
            whh_bf, xproj + (size_t)t * BB * G4,
            h_all + (size_t)t * BB * RNN,
            h_all + (size_t)(t + 1) * BB * RNN, c_buf);
    }

    k_gemm_mel<<<dim3(INDIM / 128, MROWS / 128), 512, 0, stream>>>(
        h_all + (size_t)BB * RNN, wph_bf, ctxproj, out);
    k_gate<<<MROWS / 4, 256, 0, stream>>>(h_all + (size_t)BB * RNN, W_gate,
                                          gctx, out + (size_t)BB * NMEL * TMEL);
}

// Round 20
// 695.948 us; speedup vs baseline: 1.2377x; 1.0083x over previous
//
#include <hip/hip_runtime.h>
#include <hip/hip_bf16.h>
#include <math.h>

// Problem constants
#define BB     256
#define NMEL   80
#define TMEL   800
#define NFR    16          // frames per step
#define TT     50          // decoder steps
#define RNN    1024
#define ENC    256
#define INDIM  1280        // RNN + ENC == MEL_DIM
#define G4     4096        // 4*RNN
#define MROWS  (TT*BB)     // 12800

typedef __attribute__((ext_vector_type(8))) short bf16x8;
typedef __attribute__((ext_vector_type(4))) float f32x4;

#define GAS __attribute__((address_space(1)))
#define LAS __attribute__((address_space(3)))

__device__ __forceinline__ unsigned short f2bf(float f) {
    unsigned int u = __float_as_uint(f);
    u += 0x7FFFu + ((u >> 16) & 1u);     // round-to-nearest-even
    return (unsigned short)(u >> 16);
}
__device__ __forceinline__ float bf2f(unsigned short s) {
    return __uint_as_float(((unsigned int)s) << 16);
}
__device__ __forceinline__ float fsig(float x) {      // inf-safe fast sigmoid
    return 1.f / (1.f + __expf(-x));
}
__device__ __forceinline__ float ftanh(float x) {     // tanh = 2*sig(2x)-1
    return 2.f / (1.f + __expf(-2.f * x)) - 1.f;
}

// ---------------- prep kernels ----------------

// vectorized f32 -> bf16 (n4 = n/4 16B-chunks)
__global__ void k_f32_to_bf16(const float* __restrict__ src,
                              unsigned short* __restrict__ dst, int n4) {
    for (int i = blockIdx.x * blockDim.x + threadIdx.x; i < n4;
         i += gridDim.x * blockDim.x) {
        f32x4 v = *(const f32x4*)(src + (size_t)i * 4);
        unsigned long long p = (unsigned long long)f2bf(v[0]) |
                               ((unsigned long long)f2bf(v[1]) << 16) |
                               ((unsigned long long)f2bf(v[2]) << 32) |
                               ((unsigned long long)f2bf(v[3]) << 48);
        *(unsigned long long*)(dst + (size_t)i * 4) = p;
    }
}

// W_proj[:, 0:1024] -> bf16, N-permuted: dst row m' = mel*16+fr comes from
// W_proj row m = fr*80+mel. 4-wide chunks.
__global__ void k_conv_wph(const float* __restrict__ wproj,
                           unsigned short* __restrict__ dst) {
    const int n4 = INDIM * RNN / 4;
    for (int i = blockIdx.x * blockDim.x + threadIdx.x; i < n4;
         i += gridDim.x * blockDim.x) {
        int mp = i >> 8, kc = (i & 255) * 4;
        int mel = mp >> 4, fr = mp & 15;
        f32x4 v = *(const f32x4*)(wproj + (size_t)(fr * NMEL + mel) * INDIM + kc);
        unsigned long long p = (unsigned long long)f2bf(v[0]) |
                               ((unsigned long long)f2bf(v[1]) << 16) |
                               ((unsigned long long)f2bf(v[2]) << 32) |
                               ((unsigned long long)f2bf(v[3]) << 48);
        *(unsigned long long*)(dst + (size_t)i * 4) = p;
    }
}

// W_proj[:, 1024:1280] -> bf16 [1280][256], rows permuted m' = mel*16+fr.
__global__ void k_conv_wpc(const float* __restrict__ wproj,
                           unsigned short* __restrict__ dst) {
    const int n4 = INDIM * ENC / 4;                 // 81920 chunks
    for (int i = blockIdx.x * blockDim.x + threadIdx.x; i < n4;
         i += gridDim.x * blockDim.x) {
        int mp = i >> 6, kc = (i & 63) * 4;
        int mel = mp >> 4, fr = mp & 15;
        f32x4 v = *(const f32x4*)(wproj + (size_t)(fr * NMEL + mel) * INDIM +
                                  RNN + kc);
        unsigned long long p = (unsigned long long)f2bf(v[0]) |
                               ((unsigned long long)f2bf(v[1]) << 16) |
                               ((unsigned long long)f2bf(v[2]) << 32) |
                               ((unsigned long long)f2bf(v[3]) << 48);
        *(unsigned long long*)(dst + (size_t)i * 4) = p;
    }
}

// teacher-forced inputs via LDS transpose tile: WG per (t,b).
// frames[t][b][k] = (t==0)?0:target[b][k%80][t*16+k/80]
__global__ __launch_bounds__(128) void k_frames(const float* __restrict__ target,
                                                unsigned short* __restrict__ frames) {
    const int wg = blockIdx.x;              // 0..12799
    const int t = wg >> 8, b = wg & 255;
    unsigned short* dst = frames + ((size_t)t * BB + b) * INDIM;
    if (t == 0) {
        for (int i = threadIdx.x; i < INDIM / 8; i += 128)
            *(f32x4*)(dst + i * 8) = (f32x4){0.f, 0.f, 0.f, 0.f};
        return;
    }
    __shared__ float ld[NMEL][17];
    for (int i = threadIdx.x; i < 320; i += 128) {    // 80 mel x 4 f32x4
        const int mel = i >> 2, fq = i & 3;
        f32x4 v = *(const f32x4*)(target + ((size_t)b * NMEL + mel) * TMEL +
                                  t * NFR + fq * 4);
        #pragma unroll
        for (int j = 0; j < 4; ++j) ld[mel][fq * 4 + j] = v[j];
    }
    __syncthreads();
    for (int i = threadIdx.x; i < 160; i += 128) {    // 160 x 8-short chunks
        unsigned long long p0 = 0, p1 = 0;
        #pragma unroll
        for (int j = 0; j < 4; ++j) {
            const int k = i * 8 + j;
            p0 |= (unsigned long long)f2bf(ld[k % 80][k / 80]) << (16 * j);
        }
        #pragma unroll
        for (int j = 0; j < 4; ++j) {
            const int k = i * 8 + 4 + j;
            p1 |= (unsigned long long)f2bf(ld[k % 80][k / 80]) << (16 * j);
        }
        *(unsigned long long*)(dst + i * 8) = p0;
        *(unsigned long long*)(dst + i * 8 + 4) = p1;
    }
}

// gatectx[b] = b_gate + context[b]·W_gate[0][1024:1280]  (f32x4 vectorized)
__global__ void k_gatectx(const float* __restrict__ context,
                          const float* __restrict__ wgate,
                          const float* __restrict__ bgate,
                          float* __restrict__ gctx) {
    int b = blockIdx.x * blockDim.x + threadIdx.x;
    if (b >= BB) return;
    float acc = bgate[0];
    const f32x4* cb = (const f32x4*)(context + (size_t)b * ENC);
    const f32x4* wr = (const f32x4*)(wgate + RNN);
    #pragma unroll 8
    for (int e = 0; e < ENC / 4; ++e) {
        f32x4 cv = cb[e], wv = wr[e];
        acc += cv[0] * wv[0] + cv[1] * wv[1] + cv[2] * wv[2] + cv[3] * wv[3];
    }
    gctx[b] = acc;
}

// ---------------- GEMM core v2 (proven: 169us xproj, 0 conflicts, 2 WG/CU) -
// 128x128 WG tile, BK=64, 512 thr / 8 waves (wave -> 64x32 output).
// Both-sides 8-sub XOR swizzle; 2-buffer counted-vmcnt pipeline.
template<int STRIDE, int KDIM>
__device__ __forceinline__ void gemm_core2(const unsigned short* __restrict__ A,
                                           const unsigned short* __restrict__ Bw,
                                           int mblk, int nblk,
                                           unsigned short* As,   // [2][8192]
                                           unsigned short* Bs,   // [2][8192]
                                           f32x4 acc[4][2]) {
    const int tid = threadIdx.x, lane = tid & 63, w = tid >> 6;
    const int lr = lane & 15, q = lane >> 4;
    const int wm = (w >> 2) * 64, wn = (w & 3) * 32;
    const int cc1 = tid, cc2 = tid + 512;
    const int r1 = cc1 >> 3, s1 = ((cc1 & 7) ^ (r1 & 7)) * 8;
    const int r2 = cc2 >> 3, s2 = ((cc2 & 7) ^ (r2 & 7)) * 8;
    const unsigned short* a1p = A + (size_t)(mblk + r1) * STRIDE + s1;
    const unsigned short* a2p = A + (size_t)(mblk + r2) * STRIDE + s2;
    const unsigned short* b1p = Bw + (size_t)(nblk + r1) * STRIDE + s1;
    const unsigned short* b2p = Bw + (size_t)(nblk + r2) * STRIDE + s2;

#define GSTAGE(buf, k0) do {                                                   \
    __builtin_amdgcn_global_load_lds((const GAS unsigned int*)(a1p + (k0)),    \
        (LAS unsigned int*)(As + (buf) * 8192 + w * 512), 16, 0, 0);           \
    __builtin_amdgcn_global_load_lds((const GAS unsigned int*)(a2p + (k0)),    \
        (LAS unsigned int*)(As + (buf) * 8192 + 4096 + w * 512), 16, 0, 0);    \
    __builtin_amdgcn_global_load_lds((const GAS unsigned int*)(b1p + (k0)),    \
        (LAS unsigned int*)(Bs + (buf) * 8192 + w * 512), 16, 0, 0);           \
    __builtin_amdgcn_global_load_lds((const GAS unsigned int*)(b2p + (k0)),    \
        (LAS unsigned int*)(Bs + (buf) * 8192 + 4096 + w * 512), 16, 0, 0); } while (0)

    constexpr int NIT = KDIM / 64;
    GSTAGE(0, 0);
    #pragma unroll 4
    for (int it = 0; it < NIT; ++it) {
        if (it < NIT - 1) {
            GSTAGE((it + 1) & 1, (it + 1) * 64);
            asm volatile("s_waitcnt vmcnt(4)" ::: "memory");
        } else {
            asm volatile("s_waitcnt vmcnt(0)" ::: "memory");
        }
        asm volatile("s_barrier" ::: "memory");
        __builtin_amdgcn_sched_barrier(0);
        const unsigned short* Ab = As + (it & 1) * 8192;
        const unsigned short* Bb = Bs + (it & 1) * 8192;
        #pragma unroll
        for (int ks = 0; ks < 2; ++ks) {
            const int j = (((ks * 4 + q) ^ (lr & 7)) * 8);  // swizzled 16B sub
            bf16x8 af[4], bv[2];
            #pragma unroll
            for (int mi = 0; mi < 4; ++mi)
                af[mi] = *(const bf16x8*)(Ab + (wm + mi * 16 + lr) * 64 + j);
            #pragma unroll
            for (int ni = 0; ni < 2; ++ni)
                bv[ni] = *(const bf16x8*)(Bb + (wn + ni * 16 + lr) * 64 + j);
            #pragma unroll
            for (int mi = 0; mi < 4; ++mi)
                #pragma unroll
                for (int ni = 0; ni < 2; ++ni)
                    acc[mi][ni] = __builtin_amdgcn_mfma_f32_16x16x32_bf16(
                        af[mi], bv[ni], acc[mi][ni], 0, 0, 0);
        }
        asm volatile("s_waitcnt lgkmcnt(0)" ::: "memory");
        __builtin_amdgcn_sched_barrier(0);
        asm volatile("s_barrier" ::: "memory");
    }
#undef GSTAGE
}

// GEMM 1: xproj = frames @ W_ih^T + b_ih + b_hh (bf16 out). M=12800 N=4096 K=1280
__global__ __launch_bounds__(512) void k_gemm_xproj(
    const unsigned short* __restrict__ A,   // [12800][1280]
    const unsigned short* __restrict__ Bw,  // [4096][1280]
    const float* __restrict__ b_ih, const float* __restrict__ b_hh,
    unsigned short* __restrict__ Cout)      // [12800][4096]
{
    __shared__ unsigned short As[2][8192], Bs[2][8192];   // 64KB
    f32x4 acc[4][2] = {};
    const int mblk = blockIdx.y * 128, nblk = blockIdx.x * 128;
    gemm_core2<INDIM, INDIM>(A, Bw, mblk, nblk, &As[0][0], &Bs[0][0], acc);
    const int lane = threadIdx.x & 63, w = threadIdx.x >> 6;
    const int wm = (w >> 2) * 64, wn = (w & 3) * 32;
    const int lr = lane & 15, q = lane >> 4;
    #pragma unroll
    for (int ni = 0; ni < 2; ++ni) {
        const int col = nblk + wn + ni * 16 + lr;
        const float bias = b_ih[col] + b_hh[col];
        #pragma unroll
        for (int mi = 0; mi < 4; ++mi) {
            const int row0 = mblk + wm + mi * 16 + q * 4;
            #pragma unroll
            for (int r = 0; r < 4; ++r)
                Cout[(size_t)(row0 + r) * G4 + col] = f2bf(acc[mi][ni][r] + bias);
        }
    }
}

// GEMM 2: mel = h_all[1:] @ Wp'^T + ctxproj'. txp is wave-private -> no
// __syncthreads in the epilogue (same-wave LDS deps ordered by lgkmcnt).
__global__ __launch_bounds__(512) void k_gemm_mel(
    const unsigned short* __restrict__ A,   // [12800][1024]
    const unsigned short* __restrict__ Bw,  // Wp' [1280][1024] (permuted)
    const float* __restrict__ ctxproj,      // [256][1280] (permuted)
    float* __restrict__ out0)               // [256][80][800]
{
    __shared__ unsigned short As[2][8192], Bs[2][8192];   // 64KB
    __shared__ float txp[8][16][20];        // per-wave transpose (10.25KB)
    f32x4 acc[4][2] = {};
    const int mblk = blockIdx.y * 128, nblk = blockIdx.x * 128;
    gemm_core2<RNN, RNN>(A, Bw, mblk, nblk, &As[0][0], &Bs[0][0], acc);
    const int lane = threadIdx.x & 63, w = threadIdx.x >> 6;
    const int wm = (w >> 2) * 64, wn = (w & 3) * 32;
    const int lr = lane & 15, q = lane >> 4;
    const int rbase = q * 4;
    const int rowl = lane & 15, fq = lane >> 4;   // readback roles
    #pragma unroll
    for (int mi = 0; mi < 4; ++mi) {
        const int row0 = mblk + wm + mi * 16;     // 16 rows: same t, b0..b0+15
        const int t = row0 >> 8, b0 = row0 & 255;
        #pragma unroll
        for (int ni = 0; ni < 2; ++ni) {
            const int colbase = nblk + wn + ni * 16;  // one mel, fr 0..15
            const int mel = colbase >> 4;
            #pragma unroll
            for (int r = 0; r < 4; ++r)
                txp[w][rbase + r][lr] = acc[mi][ni][r];
            const int bL = b0 + rowl;
            f32x4 v = *(const f32x4*)&txp[w][rowl][fq * 4];
            f32x4 cx = *(const f32x4*)(ctxproj + (size_t)bL * INDIM +
                                       mel * 16 + fq * 4);
            *(f32x4*)(out0 + (size_t)(bL * NMEL + mel) * TMEL +
                      t * NFR + fq * 4) = v + cx;
        }
    }
}

// GEMM 3: ctxproj' = context @ Wp_ctx'^T + b_proj (f32 out, permuted cols).
// M=256(b) N=1280(mp) K=256.
__global__ __launch_bounds__(512) void k_gemm_ctx(
    const unsigned short* __restrict__ A,   // context bf16 [256][256]
    const unsigned short* __restrict__ Bw,  // Wp_ctx' bf16 [1280][256]
    const float* __restrict__ bproj,
    float* __restrict__ ctxout)             // [256][1280] f32 (permuted)
{
    __shared__ unsigned short As[2][8192], Bs[2][8192];   // 64KB
    f32x4 acc[4][2] = {};
    const int mblk = blockIdx.y * 128, nblk = blockIdx.x * 128;
    gemm_core2<ENC, ENC>(A, Bw, mblk, nblk, &As[0][0], &Bs[0][0], acc);
    const int lane = threadIdx.x & 63, w = threadIdx.x >> 6;
    const int wm = (w >> 2) * 64, wn = (w & 3) * 32;
    const int lr = lane & 15, q = lane >> 4;
    #pragma unroll
    for (int ni = 0; ni < 2; ++ni) {
        const int mp = nblk + wn + ni * 16 + lr;
        const int mel = mp >> 4, fr = mp & 15;
        const float bias = bproj[fr * NMEL + mel];
        #pragma unroll
        for (int mi = 0; mi < 4; ++mi) {
            const int b0 = mblk + wm + mi * 16 + q * 4;
            #pragma unroll
            for (int r = 0; r < 4; ++r)
                ctxout[(size_t)(b0 + r) * INDIM + mp] = acc[mi][ni][r] + bias;
        }
    }
}

// ---------------- step 0: degenerate (h0 = 0, c0 = 0) ----------------------
// h0@Whh == 0 exactly and c1 = sig(i)*tanh(g), h1 = sig(o)*tanh(c1) — the
// full k_step GEMM collapses to an elementwise map over xproj[0]. Also makes
// the h0/c0 memsets dead (h_all[0] never read; c fully written here).
// Bit-identical numerics to k_step at t=0 (the deleted MFMA term was 0).
__global__ __launch_bounds__(256) void k_step0(
    const unsigned short* __restrict__ xproj0,  // [256][4096] bf16
    unsigned short* __restrict__ h1,            // [256][1024] bf16
    float* __restrict__ c)                      // [256][1024] f32
{
    const int i = blockIdx.x * 256 + threadIdx.x;   // 0..32767
    const int b = i >> 7, j0 = (i & 127) * 8;
    const unsigned short* xp = xproj0 + (size_t)b * G4 + j0;
    bf16x8 xi = *(const bf16x8*)(xp);               // gate i
    bf16x8 xg = *(const bf16x8*)(xp + 2 * RNN);     // gate g
    bf16x8 xo = *(const bf16x8*)(xp + 3 * RNN);     // gate o
    float cv[8];
    bf16x8 hh;
    #pragma unroll
    for (int k = 0; k < 8; ++k) {
        const float si = fsig(bf2f((unsigned short)xi[k]));
        const float sg = ftanh(bf2f((unsigned short)xg[k]));
        const float so = fsig(bf2f((unsigned short)xo[k]));
        const float cn = si * sg;                   // c_prev == 0
        cv[k] = cn;
        hh[k] = (short)f2bf(so * ftanh(cn));
    }
    *(f32x4*)(c + (size_t)b * RNN + j0)     = (f32x4){cv[0], cv[1], cv[2], cv[3]};
    *(f32x4*)(c + (size_t)b * RNN + j0 + 4) = (f32x4){cv[4], cv[5], cv[6], cv[7]};
    *(bf16x8*)(h1 + (size_t)b * RNN + j0) = hh;
}

// ---------------- per-step fused LSTM kernel (v11, best known) -------------
// 512 thr = 8 waves, wave -> gate g = w&3, m-half mh = w>>2; BK=128, 8 iters,
// FOUR 16KB buffers, 16-sub XOR swizzle, c + xg prefetched via
// global_load_lds, __expf activations, ONE merged barrier per iter, 3-deep:
//   vmcnt(8) -> lgkmcnt(0) -> s_barrier -> STAGE(it+3) -> compute(it)
__global__ __launch_bounds__(512) void k_step(
    const unsigned short* __restrict__ Whh,     // [4096][1024] bf16
    const unsigned short* __restrict__ xproj_t, // [256][4096] bf16
    const unsigned short* __restrict__ h_prev,  // [256][1024] bf16
    unsigned short* __restrict__ h_next,        // [256][1024] bf16
    float* __restrict__ c)                      // [256][1024] f32
{
    __shared__ unsigned short Abuf[4][8192];    // h 64r x 128k per buf (16KB x4)
    __shared__ unsigned short Bbuf[4][8192];    // Whh 64vr x 128k (16KB x4)
    __shared__ unsigned short xg[4096];         // xproj tile [4][64][16] (8KB)
    __shared__ float cld[64][16];               // cell state tile (4KB)
    __shared__ float gates[4][64][17];          // 17.4KB  => 157.4KB total
    const int tid = threadIdx.x, lane = tid & 63, w = tid >> 6;
    const int g = w & 3, mh = w >> 2;
    const int n0 = blockIdx.x * 16, m0 = blockIdx.y * 64;
    const int lr = lane & 15, q = lane >> 4;

    const int cc1 = tid, cc2 = tid + 512;
    const int r1 = cc1 >> 4, s1g = (cc1 & 15) ^ (r1 & 15);
    const int r2 = cc2 >> 4, s2g = (cc2 & 15) ^ (r2 & 15);
    const unsigned short* a1src = h_prev + (size_t)(m0 + r1) * RNN + s1g * 8;
    const unsigned short* a2src = h_prev + (size_t)(m0 + r2) * RNN + s2g * 8;
    const unsigned short* b1src = Whh +
        (size_t)((r1 >> 4) * RNN + n0 + (r1 & 15)) * RNN + s1g * 8;
    const unsigned short* b2src = Whh +
        (size_t)((r2 >> 4) * RNN + n0 + (r2 & 15)) * RNN + s2g * 8;
    const unsigned short* xsrc = xproj_t +
        (size_t)(m0 + ((tid >> 1) & 63)) * G4 + (tid >> 7) * RNN + n0 +
        (tid & 1) * 8;
    const float* csrc = c + (size_t)(m0 + (tid >> 2)) * RNN + n0 + (tid & 3) * 4;

#define STAGE(buf, k0) do {                                                    \
    __builtin_amdgcn_global_load_lds((const GAS unsigned int*)(a1src + (k0)),  \
        (LAS unsigned int*)&Abuf[buf][w * 512], 16, 0, 0);                     \
    __builtin_amdgcn_global_load_lds((const GAS unsigned int*)(a2src + (k0)),  \
        (LAS unsigned int*)&Abuf[buf][4096 + w * 512], 16, 0, 0);              \
    __builtin_amdgcn_global_load_lds((const GAS unsigned int*)(b1src + (k0)),  \
        (LAS unsigned int*)&Bbuf[buf][w * 512], 16, 0, 0);                     \
    __builtin_amdgcn_global_load_lds((const GAS unsigned int*)(b2src + (k0)),  \
        (LAS unsigned int*)&Bbuf[buf][4096 + w * 512], 16, 0, 0); } while (0)

    // oldest ops first: c (tail input), xg (epilogue input)
    if (w < 4)
        __builtin_amdgcn_global_load_lds((const GAS unsigned int*)csrc,
            (LAS unsigned int*)&cld[w * 16][0], 16, 0, 0);
    __builtin_amdgcn_global_load_lds((const GAS unsigned int*)xsrc,
        (LAS unsigned int*)&xg[w * 512], 16, 0, 0);
    STAGE(0, 0); STAGE(1, 128); STAGE(2, 256);   // 3-deep prologue

    f32x4 acc[2] = {};
    #pragma unroll
    for (int it = 0; it < 8; ++it) {
        // wait for stage(it); stages it+1, it+2 (8 ops) may stay in flight
        if (it <= 5)      asm volatile("s_waitcnt vmcnt(8)" ::: "memory");
        else if (it == 6) asm volatile("s_waitcnt vmcnt(4)" ::: "memory");
        else              asm volatile("s_waitcnt vmcnt(0)" ::: "memory");
        asm volatile("s_waitcnt lgkmcnt(0)" ::: "memory");  // my it-1 reads done
        asm volatile("s_barrier" ::: "memory");
        __builtin_amdgcn_sched_barrier(0);
        if (it <= 4) STAGE((it + 3) & 3, (it + 3) * 128);   // safe post-barrier
        const unsigned short* Ab = Abuf[it & 3];
        const unsigned short* Bb = Bbuf[it & 3];
        #pragma unroll
        for (int ks = 0; ks < 4; ++ks) {
            const int j = ((ks * 4 + q) ^ lr) * 8;   // swizzled 16B sub-chunk
            bf16x8 a0 = *(const bf16x8*)(Ab + (mh * 32 + lr) * 128 + j);
            bf16x8 a1 = *(const bf16x8*)(Ab + (mh * 32 + 16 + lr) * 128 + j);
            bf16x8 bv = *(const bf16x8*)(Bb + (g * 16 + lr) * 128 + j);
            acc[0] = __builtin_amdgcn_mfma_f32_16x16x32_bf16(a0, bv, acc[0], 0, 0, 0);
            acc[1] = __builtin_amdgcn_mfma_f32_16x16x32_bf16(a1, bv, acc[1], 0, 0, 0);
        }
    }

    // epilogue: gates = acc + xg (wave-exclusive (g, mh) rows)
    #pragma unroll
    for (int mi = 0; mi < 2; ++mi)
        #pragma unroll
        for (int r = 0; r < 4; ++r) {
            const int row = mh * 32 + mi * 16 + q * 4 + r;
            gates[g][row][lr] = acc[mi][r] +
                bf2f(xg[(g * 64 + row) * 16 + lr]);
        }
    __syncthreads();

    // LSTM tail: 1024 elements (64x16), 2 per thread; c from LDS prefetch
    #pragma unroll
    for (int q2 = 0; q2 < 2; ++q2) {
        const int e = tid + q2 * 512;
        const int row = e >> 4, col = e & 15;
        const int b = m0 + row, j = n0 + col;
        const float xi = gates[0][row][col];
        const float xf = gates[1][row][col];
        const float xgt = gates[2][row][col];
        const float xo = gates[3][row][col];
        const float si = fsig(xi);
        const float sf = fsig(xf);
        const float so = fsig(xo);
        const float cp = cld[row][col];
        const float cn = sf * cp + si * ftanh(xgt);
        const float hn = so * ftanh(cn);
        c[(size_t)b * RNN + j] = cn;
        h_next[(size_t)b * RNN + j] = f2bf(hn);
    }
#undef STAGE
}

// gate[b*50+t] = gatectx[b] + h_all[t+1][b]·w_gate[0:1024] ; one wave per row
__global__ void k_gate(const unsigned short* __restrict__ h,  // [12800][1024]
                       const float* __restrict__ wgate,
                       const float* __restrict__ gctx,
                       float* __restrict__ out1) {
    const int gw = (blockIdx.x * blockDim.x + threadIdx.x) >> 6;
    const int lane = threadIdx.x & 63;
    if (gw >= MROWS) return;
    const unsigned short* hr = h + (size_t)gw * RNN + lane * 16;
    const float* wr = wgate + lane * 16;
    float acc = 0.f;
    #pragma unroll
    for (int j = 0; j < 16; ++j) acc += bf2f(hr[j]) * wr[j];
    for (int off = 32; off; off >>= 1) acc += __shfl_down(acc, off);
    if (lane == 0) {
        const int t = gw >> 8, b = gw & 255;
        out1[b * TT + t] = acc + gctx[b];
    }
}

// ---------------- workspace layout (all offsets 1KB-aligned) ----------------
static const size_t OFF_WIH   = 0;                                    // 10.5 MB
static const size_t OFF_WHH   = OFF_WIH   + (size_t)G4 * INDIM * 2;   // 8 MB
static const size_t OFF_WPH   = OFF_WHH   + (size_t)G4 * RNN * 2;     // 2.6 MB
static const size_t OFF_WPC   = OFF_WPH   + (size_t)INDIM * RNN * 2;  // 0.65 MB
static const size_t OFF_CTXB  = OFF_WPC   + (size_t)INDIM * ENC * 2;  // 128 KB
static const size_t OFF_FRM   = OFF_CTXB  + (size_t)BB * ENC * 2;     // 32.8 MB
static const size_t OFF_XPROJ = OFF_FRM   + (size_t)MROWS * INDIM * 2;// 104.9 MB
static const size_t OFF_HALL  = OFF_XPROJ + (size_t)MROWS * G4 * 2;   // 26.7 MB
static const size_t OFF_C     = OFF_HALL  + (size_t)(TT + 1) * BB * RNN * 2;
static const size_t OFF_CTX   = OFF_C     + (size_t)BB * RNN * 4;
static const size_t OFF_GCTX  = OFF_CTX   + (size_t)BB * INDIM * 4;

extern "C" void kernel_launch(void* const* d_in, const int* in_sizes, int n_in,
                              void* d_out, int out_size, void* d_ws, size_t ws_size,
                              hipStream_t stream) {
    const float* context = (const float*)d_in[0];
    const float* target  = (const float*)d_in[1];
    const float* W_ih    = (const float*)d_in[2];
    const float* b_ih    = (const float*)d_in[3];
    const float* W_hh    = (const float*)d_in[4];
    const float* b_hh    = (const float*)d_in[5];
    const float* W_proj  = (const float*)d_in[6];
    const float* b_proj  = (const float*)d_in[7];
    const float* W_gate  = (const float*)d_in[8];
    const float* b_gate  = (const float*)d_in[9];
    float* out = (float*)d_out;
    char* ws = (char*)d_ws;

    unsigned short* wih_bf  = (unsigned short*)(ws + OFF_WIH);
    unsigned short* whh_bf  = (unsigned short*)(ws + OFF_WHH);
    unsigned short* wph_bf  = (unsigned short*)(ws + OFF_WPH);
    unsigned short* wpc_bf  = (unsigned short*)(ws + OFF_WPC);
    unsigned short* ctx_bf  = (unsigned short*)(ws + OFF_CTXB);
    unsigned short* frames  = (unsigned short*)(ws + OFF_FRM);
    unsigned short* xproj   = (unsigned short*)(ws + OFF_XPROJ);
    unsigned short* h_all   = (unsigned short*)(ws + OFF_HALL);
    float*          c_buf   = (float*)(ws + OFF_C);
    float*          ctxproj = (float*)(ws + OFF_CTX);
    float*          gctx    = (float*)(ws + OFF_GCTX);

    k_f32_to_bf16<<<2048, 256, 0, stream>>>(W_ih, wih_bf, G4 * INDIM / 4);
    k_f32_to_bf16<<<2048, 256, 0, stream>>>(W_hh, whh_bf, G4 * RNN / 4);
    k_conv_wph<<<2048, 256, 0, stream>>>(W_proj, wph_bf);
    k_conv_wpc<<<320, 256, 0, stream>>>(W_proj, wpc_bf);
    k_f32_to_bf16<<<64, 256, 0, stream>>>(context, ctx_bf, BB * ENC / 4);
    k_frames<<<MROWS, 128, 0, stream>>>(target, frames);
    k_gatectx<<<1, 256, 0, stream>>>(context, W_gate, b_gate, gctx);

    k_gemm_ctx<<<dim3(INDIM / 128, BB / 128), 512, 0, stream>>>(
        ctx_bf, wpc_bf, b_proj, ctxproj);

    k_gemm_xproj<<<dim3(G4 / 128, MROWS / 128), 512, 0, stream>>>(
        frames, wih_bf, b_ih, b_hh, xproj);

    // step 0 is degenerate (h0 = c0 = 0): elementwise over xproj[0].
    // Writes all of c_buf and h_all[1]; h_all[0] is never read -> no memsets.
    k_step0<<<128, 256, 0, stream>>>(xproj, h_all + (size_t)BB * RNN, c_buf);

    for (int t = 1; t < TT; ++t) {
        k_step<<<dim3(64, 4), 512, 0, stream>>>(
            whh_bf, xproj + (size_t)t * BB * G4,
            h_all + (size_t)t * BB * RNN,
            h_all + (size_t)(t + 1) * BB * RNN, c_buf);
    }

    k_gemm_mel<<<dim3(INDIM / 128, MROWS / 128), 512, 0, stream>>>(
        h_all + (size_t)BB * RNN, wph_bf, ctxproj, out);
    k_gate<<<MROWS / 4, 256, 0, stream>>>(h_all + (size_t)BB * RNN, W_gate,
                                          gctx, out + (size_t)BB * NMEL * TMEL);
}